// Round 11
// baseline (54.438 us; speedup 1.0000x reference)
//
#include <hip/hip_runtime.h>
#include <stdint.h>

typedef __attribute__((ext_vector_type(8))) short short8;
typedef __attribute__((ext_vector_type(4))) float f32x4;
typedef __attribute__((ext_vector_type(4))) uint32_t u32x4;

#define K_DIM 4096
#define N_DIM 128
#define M_DIM 4096
#define MN ((size_t)M_DIM * N_DIM)
#define NS 8
#define BK 64
#define FRAG_PER_SLAB MN

__device__ __forceinline__ uint16_t f2bf(float f) {
    uint32_t u = __float_as_uint(f);
    return (uint16_t)((u + 0x7FFFu + ((u >> 16) & 1u)) >> 16);
}
__device__ __forceinline__ float bf2f(uint16_t h) {
    return __uint_as_float((uint32_t)h << 16);
}

__device__ __forceinline__ short8 cvt8(const float4 lo, const float4 hi) {
    short8 r;
    r[0] = (short)f2bf(lo.x); r[1] = (short)f2bf(lo.y);
    r[2] = (short)f2bf(lo.z); r[3] = (short)f2bf(lo.w);
    r[4] = (short)f2bf(hi.x); r[5] = (short)f2bf(hi.y);
    r[6] = (short)f2bf(hi.z); r[7] = (short)f2bf(hi.w);
    return r;
}

// ---- prep: W f32 -> bf16 (3 matrices of 128 x 4096) ----
__global__ __launch_bounds__(256) void prep_kernel(
    const float* __restrict__ W0, const float* __restrict__ W1,
    const float* __restrict__ W2, uint16_t* __restrict__ Wb)
{
    int gid = blockIdx.x * 256 + threadIdx.x;   // 0 .. 196607
    int g = gid >> 16;                          // 65536 threads per matrix
    int e = (gid & 65535) * 8;
    const float* W = (g == 0) ? W0 : (g == 1) ? W1 : W2;
    float4 lo = *(const float4*)(W + e);
    float4 hi = *(const float4*)(W + e + 4);
    *(short8*)(Wb + (size_t)g * (N_DIM * K_DIM) + e) = cvt8(lo, hi);
}

// ---- GEMM, K-split NS=8, BK=64, depth-1 counted vmcnt, TWO barriers/iter ----
// Per-iter data path identical to R0/R3/R8 (verified): 16 MFMA + 8 ds_read_b128
// + 4 global_load_lds + 4 A-float4 per wave, granule-swizzled staging, 0 bank
// conflicts. 2 x 16KB buffers (32 KB LDS) + __launch_bounds__(256,5) -> 5
// resident blocks/CU (20 waves/CU); NS=8 -> 1536 blocks demands 6/CU.
// Schedule per iter kt:
//   lgkmcnt(0); s_barrier        -- all waves done READING buf (kt+1)&1
//   issue BATCH(kt+1)            -- 8 vmem into buf (kt+1)&1 (write-after-read safe)
//   s_waitcnt vmcnt(8)           -- MY batch kt landed (8 newest = batch kt+1)
//   s_barrier                    -- R9-NaN fix: vmcnt is PER-WAVE; this barrier
//                                   proves ALL waves' batch kt landed before any
//                                   wave reads the buffer they staged.
//   compute buf kt&1             -- never vmcnt(0) mid-loop: HBM pipe stays full
__global__ __launch_bounds__(256, 5) void gemm3_kernel(
    const float* __restrict__ x0, const float* __restrict__ x1,
    const float* __restrict__ x2, const uint16_t* __restrict__ Wb,
    uint16_t* __restrict__ zpart)
{
    __shared__ uint16_t lds[2][8192];   // 2 x 16 KiB: [col(128)][granule(8) of 8 bf16]

    const int tid  = threadIdx.x;
    const int lane = tid & 63;
    const int wv   = tid >> 6;

    const int lid = (blockIdx.x & 7) * 192 + (blockIdx.x >> 3);  // XCD-contig
    const int g   = lid >> 9;
    const int rem = lid & 511;
    const int ks  = rem >> 6;
    const int mt  = rem & 63;
    const int k0  = ks * (K_DIM / NS);               // K-chunk of 512, NT=8

    const float* x = (g == 0) ? x0 : (g == 1) ? x1 : x2;
    const uint16_t* Wg = Wb + (size_t)g * (N_DIM * K_DIM);

    const int c16 = lane & 15;
    const int qg  = lane >> 4;
    const int rowbase = mt * 64 + wv * 16;
    const float* aptr = x + (size_t)(rowbase + c16) * K_DIM + qg * 8 + k0;

    // staging sources (R0/R3-verified): col = c*32 + (tid>>3), slot = tid&7,
    // granule = slot ^ (col&7)
    const int t8 = tid >> 3, slot = tid & 7;
    const uint16_t* wsrc[4];
#pragma unroll
    for (int c = 0; c < 4; ++c) {
        int col = c * 32 + t8;
        wsrc[c] = Wg + (size_t)col * K_DIM + (slot ^ (col & 7)) * 8 + k0;
    }

    f32x4 acc[8];
#pragma unroll
    for (int nf = 0; nf < 8; ++nf) acc[nf] = (f32x4)0.f;

    float4 areg[2][4];

#define STAGE(B, KB) do {                                                      \
    _Pragma("unroll")                                                          \
    for (int c = 0; c < 4; ++c) {                                              \
        __builtin_amdgcn_global_load_lds(                                      \
            (const __attribute__((address_space(1))) uint32_t*)(wsrc[c] + (KB)), \
            (__attribute__((address_space(3))) uint32_t*)&lds[B][c * 2048 + wv * 512], \
            16, 0, 0);                                                         \
    }                                                                          \
  } while (0)

#define BATCH(B, KB) do {                                                      \
    STAGE(B, KB);                                                              \
    areg[B][0] = *(const float4*)(aptr + (KB));                                \
    areg[B][1] = *(const float4*)(aptr + (KB) + 4);                            \
    areg[B][2] = *(const float4*)(aptr + (KB) + 32);                           \
    areg[B][3] = *(const float4*)(aptr + (KB) + 36);                           \
  } while (0)

#define ITER(SLOT, KT, VM, ISSUE) do {                                         \
    asm volatile("s_waitcnt lgkmcnt(0)" ::: "memory");                         \
    asm volatile("s_barrier" ::: "memory");                                    \
    if (ISSUE) { BATCH(((SLOT) ^ 1), (((KT) + 1) * BK)); }                     \
    asm volatile("s_waitcnt vmcnt(%0)" :: "i"(VM) : "memory");                 \
    asm volatile("s_barrier" ::: "memory");                                    \
    _Pragma("unroll")                                                          \
    for (int h = 0; h < 2; ++h) {                                              \
        short8 af = cvt8(areg[SLOT][2 * h], areg[SLOT][2 * h + 1]);            \
        const int boff = c16 * 64 + (((h * 4) + qg) ^ (lane & 7)) * 8;         \
        _Pragma("unroll")                                                      \
        for (int nf = 0; nf < 8; ++nf) {                                       \
            short8 bf = *(const short8*)&lds[SLOT][nf * 1024 + boff];          \
            acc[nf] = __builtin_amdgcn_mfma_f32_16x16x32_bf16(af, bf, acc[nf], 0, 0, 0); \
        }                                                                      \
    }                                                                          \
  } while (0)

    // prologue: batch for iter 0 (depth-1 pipeline)
    BATCH(0, 0);

    ITER(0, 0, 8, true);
    ITER(1, 1, 8, true);
    ITER(0, 2, 8, true);
    ITER(1, 3, 8, true);
    ITER(0, 4, 8, true);
    ITER(1, 5, 8, true);
    ITER(0, 6, 8, true);      // issues batch 7 -> buf1
    ITER(1, 7, 0, false);

#undef ITER
#undef BATCH
#undef STAGE

    // fragment-packed bf16 epilogue (R4/R7/R8-verified): 4 x 16B contiguous stores
    uint32_t dw[16];
#pragma unroll
    for (int nf = 0; nf < 8; ++nf) {
        dw[nf * 2]     = (uint32_t)f2bf(acc[nf][0]) | ((uint32_t)f2bf(acc[nf][1]) << 16);
        dw[nf * 2 + 1] = (uint32_t)f2bf(acc[nf][2]) | ((uint32_t)f2bf(acc[nf][3]) << 16);
    }
    uint16_t* zp = zpart + (size_t)(ks * 3 + g) * FRAG_PER_SLAB
                 + (size_t)mt * 8192 + (size_t)(wv * 64 + lane) * 32;
    uint32_t* zp32 = (uint32_t*)zp;
#pragma unroll
    for (int j = 0; j < 4; ++j) {
        u32x4 v = { dw[j * 4], dw[j * 4 + 1], dw[j * 4 + 2], dw[j * 4 + 3] };
        *(u32x4*)(zp32 + j * 4) = v;
    }
}

// ---- combine: sum NS=8 bf16 partials per (g, element) in fragment order,
// write aligned (scatter decode), per-block loss partials ----
__global__ __launch_bounds__(256) void combine_kernel(
    const uint16_t* __restrict__ zpart, float* __restrict__ out,
    float* __restrict__ partials)
{
    const int tid  = threadIdx.x;
    const int gtid = blockIdx.x * 256 + tid;        // 65536 threads
    const size_t F0 = (size_t)gtid * 8;             // 8 consecutive frag vals

    const int idx_base = (int)(F0 & 31);            // 0,8,16,24
    const int lane = (int)((F0 >> 5) & 63);
    const int wv   = (int)((F0 >> 11) & 3);
    const int mt   = (int)(F0 >> 13);
    const int c16  = lane & 15;
    const int qg   = lane >> 4;
    const int rowb = mt * 64 + wv * 16 + qg * 4;

    float zs[3][8];
#pragma unroll
    for (int g = 0; g < 3; ++g)
#pragma unroll
        for (int v = 0; v < 8; ++v) zs[g][v] = 0.f;

#pragma unroll
    for (int ks = 0; ks < NS; ++ks) {
#pragma unroll
        for (int g = 0; g < 3; ++g) {
            const short8 pv = *(const short8*)(zpart + (size_t)(ks * 3 + g) * FRAG_PER_SLAB + F0);
#pragma unroll
            for (int v = 0; v < 8; ++v) zs[g][v] += bf2f((uint16_t)pv[v]);
        }
    }

    float s = 0.f;
#pragma unroll
    for (int v = 0; v < 8; ++v) {
        const float a = zs[0][v], b = zs[1][v], c = zs[2][v];
        const int idx = idx_base + v;
        const int nf = idx >> 2, r = idx & 3;
        out[(size_t)(rowb + r) * N_DIM + nf * 16 + c16] = (a + b + c) * (1.f / 3.f);
        const float d1 = a - b, d2 = a - c, d3 = b - c;
        s += d1 * d1 + d2 * d2 + d3 * d3;
    }

#pragma unroll
    for (int off = 32; off > 0; off >>= 1) s += __shfl_xor(s, off);
    __shared__ float wsum[4];
    if ((tid & 63) == 0) wsum[tid >> 6] = s;
    __syncthreads();
    if (tid == 0) partials[blockIdx.x] = wsum[0] + wsum[1] + wsum[2] + wsum[3];
}

__global__ __launch_bounds__(256) void finalize_kernel(
    const float* __restrict__ partials, float* __restrict__ out)
{
    const int tid = threadIdx.x;
    float s = partials[tid];
#pragma unroll
    for (int off = 32; off > 0; off >>= 1) s += __shfl_xor(s, off);
    __shared__ float wsum[4];
    if ((tid & 63) == 0) wsum[tid >> 6] = s;
    __syncthreads();
    if (tid == 0)
        out[MN] = (wsum[0] + wsum[1] + wsum[2] + wsum[3]) * (1.f / 12288.f) - 0.05f;
}

extern "C" void kernel_launch(void* const* d_in, const int* in_sizes, int n_in,
                              void* d_out, int out_size, void* d_ws, size_t ws_size,
                              hipStream_t stream)
{
    const float* x0 = (const float*)d_in[0];
    const float* x1 = (const float*)d_in[1];
    const float* x2 = (const float*)d_in[2];
    const float* W0 = (const float*)d_in[3];
    const float* W1 = (const float*)d_in[4];
    const float* W2 = (const float*)d_in[5];
    float* out = (float*)d_out;

    const size_t zpart_bytes = (size_t)NS * 3 * FRAG_PER_SLAB * sizeof(uint16_t); // 25,165,824
    const size_t wb_bytes    = (size_t)3 * N_DIM * K_DIM * sizeof(uint16_t);      //  3,145,728

    char* ws = (char*)d_ws;
    uint16_t* zpart    = (uint16_t*)ws;
    uint16_t* Wb       = (uint16_t*)(ws + zpart_bytes);
    float*    partials = (float*)(ws + zpart_bytes + wb_bytes);

    prep_kernel    <<< 768, 256, 0, stream>>>(W0, W1, W2, Wb);
    gemm3_kernel   <<<1536, 256, 0, stream>>>(x0, x1, x2, Wb, zpart);
    combine_kernel <<< 256, 256, 0, stream>>>(zpart, out, partials);
    finalize_kernel<<<   1, 256, 0, stream>>>(partials, out);
}

// Round 12
// 51.847 us; speedup vs baseline: 1.0500x; 1.0500x over previous
//
#include <hip/hip_runtime.h>
#include <stdint.h>

typedef __attribute__((ext_vector_type(8))) short short8;
typedef __attribute__((ext_vector_type(4))) float f32x4;
typedef __attribute__((ext_vector_type(4))) uint32_t u32x4;

#define K_DIM 4096
#define N_DIM 128
#define M_DIM 4096
#define MN ((size_t)M_DIM * N_DIM)
#define NS 4
#define BK 64
#define FRAG_PER_SLAB MN

__device__ __forceinline__ uint16_t f2bf(float f) {
    uint32_t u = __float_as_uint(f);
    return (uint16_t)((u + 0x7FFFu + ((u >> 16) & 1u)) >> 16);
}
__device__ __forceinline__ float bf2f(uint16_t h) {
    return __uint_as_float((uint32_t)h << 16);
}

__device__ __forceinline__ short8 cvt8(const float4 lo, const float4 hi) {
    short8 r;
    r[0] = (short)f2bf(lo.x); r[1] = (short)f2bf(lo.y);
    r[2] = (short)f2bf(lo.z); r[3] = (short)f2bf(lo.w);
    r[4] = (short)f2bf(hi.x); r[5] = (short)f2bf(hi.y);
    r[6] = (short)f2bf(hi.z); r[7] = (short)f2bf(hi.w);
    return r;
}

// ---- prep: W f32 -> bf16 (3 matrices of 128 x 4096) ----
__global__ __launch_bounds__(256) void prep_kernel(
    const float* __restrict__ W0, const float* __restrict__ W1,
    const float* __restrict__ W2, uint16_t* __restrict__ Wb)
{
    int gid = blockIdx.x * 256 + threadIdx.x;   // 0 .. 196607
    int g = gid >> 16;                          // 65536 threads per matrix
    int e = (gid & 65535) * 8;
    const float* W = (g == 0) ? W0 : (g == 1) ? W1 : W2;
    float4 lo = *(const float4*)(W + e);
    float4 hi = *(const float4*)(W + e + 4);
    *(short8*)(Wb + (size_t)g * (N_DIM * K_DIM) + e) = cvt8(lo, hi);
}

// ---- GEMM, K-split NS=4, BK=64 (best-measured config, R8 = 51.99 us) ----
// 16 MFMA + 8 ds_read_b128 + 4 global_load_lds + 4 A-float4 per wave per iter;
// counted-vmcnt depth-2 over THREE 16KB LDS buffers (48 KB -> 3 blocks/CU).
// Iter kt: lgkmcnt(0); s_barrier; issue batch kt+2 into buf (kt+2)%3;
// s_waitcnt vmcnt(16) -- 2 newest batches in flight, batch kt landed. Never
// vmcnt(0) mid-loop. Depth-2 gives a full iteration of cross-wave slack, so
// no post-vmcnt barrier is needed (R8-verified correct; R9's depth-1 raced).
__global__ __launch_bounds__(256, 3) void gemm3_kernel(
    const float* __restrict__ x0, const float* __restrict__ x1,
    const float* __restrict__ x2, const uint16_t* __restrict__ Wb,
    uint16_t* __restrict__ zpart)
{
    __shared__ uint16_t lds[3][8192];   // 3 x 16 KiB: [col(128)][granule(8) of 8 bf16]

    const int tid  = threadIdx.x;
    const int lane = tid & 63;
    const int wv   = tid >> 6;

    const int lid = (blockIdx.x & 7) * 96 + (blockIdx.x >> 3);   // XCD-contig
    const int g   = lid >> 8;
    const int rem = lid & 255;
    const int ks  = rem >> 6;
    const int mt  = rem & 63;
    const int k0  = ks * (K_DIM / NS);               // K-chunk of 1024, NT=16

    const float* x = (g == 0) ? x0 : (g == 1) ? x1 : x2;
    const uint16_t* Wg = Wb + (size_t)g * (N_DIM * K_DIM);

    const int c16 = lane & 15;
    const int qg  = lane >> 4;
    const int rowbase = mt * 64 + wv * 16;
    const float* aptr = x + (size_t)(rowbase + c16) * K_DIM + qg * 8 + k0;

    // staging sources (R0/R3-verified): col = c*32 + (tid>>3), slot = tid&7,
    // granule = slot ^ (col&7)
    const int t8 = tid >> 3, slot = tid & 7;
    const uint16_t* wsrc[4];
#pragma unroll
    for (int c = 0; c < 4; ++c) {
        int col = c * 32 + t8;
        wsrc[c] = Wg + (size_t)col * K_DIM + (slot ^ (col & 7)) * 8 + k0;
    }

    f32x4 acc[8];
#pragma unroll
    for (int nf = 0; nf < 8; ++nf) acc[nf] = (f32x4)0.f;

    float4 areg[3][4];

#define STAGE(B, KB) do {                                                      \
    _Pragma("unroll")                                                          \
    for (int c = 0; c < 4; ++c) {                                              \
        __builtin_amdgcn_global_load_lds(                                      \
            (const __attribute__((address_space(1))) uint32_t*)(wsrc[c] + (KB)), \
            (__attribute__((address_space(3))) uint32_t*)&lds[B][c * 2048 + wv * 512], \
            16, 0, 0);                                                         \
    }                                                                          \
  } while (0)

#define BATCH(B, KB) do {                                                      \
    STAGE(B, KB);                                                              \
    areg[B][0] = *(const float4*)(aptr + (KB));                                \
    areg[B][1] = *(const float4*)(aptr + (KB) + 4);                            \
    areg[B][2] = *(const float4*)(aptr + (KB) + 32);                           \
    areg[B][3] = *(const float4*)(aptr + (KB) + 36);                           \
  } while (0)

#define ITER(SLOT, KT, VM, ISSUE) do {                                         \
    asm volatile("s_waitcnt lgkmcnt(0)" ::: "memory");                         \
    asm volatile("s_barrier" ::: "memory");                                    \
    if (ISSUE) { BATCH((((SLOT) + 2) % 3), (((KT) + 2) * BK)); }               \
    asm volatile("s_waitcnt vmcnt(%0)" :: "i"(VM) : "memory");                 \
    _Pragma("unroll")                                                          \
    for (int h = 0; h < 2; ++h) {                                              \
        short8 af = cvt8(areg[SLOT][2 * h], areg[SLOT][2 * h + 1]);            \
        const int boff = c16 * 64 + (((h * 4) + qg) ^ (lane & 7)) * 8;         \
        _Pragma("unroll")                                                      \
        for (int nf = 0; nf < 8; ++nf) {                                       \
            short8 bf = *(const short8*)&lds[SLOT][nf * 1024 + boff];          \
            acc[nf] = __builtin_amdgcn_mfma_f32_16x16x32_bf16(af, bf, acc[nf], 0, 0, 0); \
        }                                                                      \
    }                                                                          \
  } while (0)

    // prologue: batches for iters 0 and 1
    BATCH(0, 0);
    BATCH(1, BK);

#pragma unroll
    for (int kt = 0; kt < 12; kt += 3) {
        ITER(0, kt + 0, 16, true);
        ITER(1, kt + 1, 16, true);
        ITER(2, kt + 2, 16, true);
    }
    ITER(0, 12, 16, true);    // issues kt14 -> buf2
    ITER(1, 13, 16, true);    // issues kt15 -> buf0
    ITER(2, 14,  8, false);
    ITER(0, 15,  0, false);

#undef ITER
#undef BATCH
#undef STAGE

    // fragment-packed bf16 epilogue (R4/R7/R8-verified): 4 x 16B contiguous stores
    uint32_t dw[16];
#pragma unroll
    for (int nf = 0; nf < 8; ++nf) {
        dw[nf * 2]     = (uint32_t)f2bf(acc[nf][0]) | ((uint32_t)f2bf(acc[nf][1]) << 16);
        dw[nf * 2 + 1] = (uint32_t)f2bf(acc[nf][2]) | ((uint32_t)f2bf(acc[nf][3]) << 16);
    }
    uint16_t* zp = zpart + (size_t)(ks * 3 + g) * FRAG_PER_SLAB
                 + (size_t)mt * 8192 + (size_t)(wv * 64 + lane) * 32;
    uint32_t* zp32 = (uint32_t*)zp;
#pragma unroll
    for (int j = 0; j < 4; ++j) {
        u32x4 v = { dw[j * 4], dw[j * 4 + 1], dw[j * 4 + 2], dw[j * 4 + 3] };
        *(u32x4*)(zp32 + j * 4) = v;
    }
}

// ---- combine: sum NS=4 bf16 partials per (g, element) in fragment order,
// write aligned (scatter decode), per-block loss partials ----
__global__ __launch_bounds__(256) void combine_kernel(
    const uint16_t* __restrict__ zpart, float* __restrict__ out,
    float* __restrict__ partials)
{
    const int tid  = threadIdx.x;
    const int gtid = blockIdx.x * 256 + tid;        // 65536 threads
    const size_t F0 = (size_t)gtid * 8;             // 8 consecutive frag vals

    const int idx_base = (int)(F0 & 31);            // 0,8,16,24
    const int lane = (int)((F0 >> 5) & 63);
    const int wv   = (int)((F0 >> 11) & 3);
    const int mt   = (int)(F0 >> 13);
    const int c16  = lane & 15;
    const int qg   = lane >> 4;
    const int rowb = mt * 64 + wv * 16 + qg * 4;

    float zs[3][8];
#pragma unroll
    for (int g = 0; g < 3; ++g)
#pragma unroll
        for (int v = 0; v < 8; ++v) zs[g][v] = 0.f;

#pragma unroll
    for (int ks = 0; ks < NS; ++ks) {
#pragma unroll
        for (int g = 0; g < 3; ++g) {
            const short8 pv = *(const short8*)(zpart + (size_t)(ks * 3 + g) * FRAG_PER_SLAB + F0);
#pragma unroll
            for (int v = 0; v < 8; ++v) zs[g][v] += bf2f((uint16_t)pv[v]);
        }
    }

    float s = 0.f;
#pragma unroll
    for (int v = 0; v < 8; ++v) {
        const float a = zs[0][v], b = zs[1][v], c = zs[2][v];
        const int idx = idx_base + v;
        const int nf = idx >> 2, r = idx & 3;
        out[(size_t)(rowb + r) * N_DIM + nf * 16 + c16] = (a + b + c) * (1.f / 3.f);
        const float d1 = a - b, d2 = a - c, d3 = b - c;
        s += d1 * d1 + d2 * d2 + d3 * d3;
    }

#pragma unroll
    for (int off = 32; off > 0; off >>= 1) s += __shfl_xor(s, off);
    __shared__ float wsum[4];
    if ((tid & 63) == 0) wsum[tid >> 6] = s;
    __syncthreads();
    if (tid == 0) partials[blockIdx.x] = wsum[0] + wsum[1] + wsum[2] + wsum[3];
}

__global__ __launch_bounds__(256) void finalize_kernel(
    const float* __restrict__ partials, float* __restrict__ out)
{
    const int tid = threadIdx.x;
    float s = partials[tid];
#pragma unroll
    for (int off = 32; off > 0; off >>= 1) s += __shfl_xor(s, off);
    __shared__ float wsum[4];
    if ((tid & 63) == 0) wsum[tid >> 6] = s;
    __syncthreads();
    if (tid == 0)
        out[MN] = (wsum[0] + wsum[1] + wsum[2] + wsum[3]) * (1.f / 12288.f) - 0.05f;
}

extern "C" void kernel_launch(void* const* d_in, const int* in_sizes, int n_in,
                              void* d_out, int out_size, void* d_ws, size_t ws_size,
                              hipStream_t stream)
{
    const float* x0 = (const float*)d_in[0];
    const float* x1 = (const float*)d_in[1];
    const float* x2 = (const float*)d_in[2];
    const float* W0 = (const float*)d_in[3];
    const float* W1 = (const float*)d_in[4];
    const float* W2 = (const float*)d_in[5];
    float* out = (float*)d_out;

    const size_t zpart_bytes = (size_t)NS * 3 * FRAG_PER_SLAB * sizeof(uint16_t); // 12,582,912
    const size_t wb_bytes    = (size_t)3 * N_DIM * K_DIM * sizeof(uint16_t);      //  3,145,728

    char* ws = (char*)d_ws;
    uint16_t* zpart    = (uint16_t*)ws;
    uint16_t* Wb       = (uint16_t*)(ws + zpart_bytes);
    float*    partials = (float*)(ws + zpart_bytes + wb_bytes);

    prep_kernel    <<<768, 256, 0, stream>>>(W0, W1, W2, Wb);
    gemm3_kernel   <<<768, 256, 0, stream>>>(x0, x1, x2, Wb, zpart);
    combine_kernel <<<256, 256, 0, stream>>>(zpart, out, partials);
    finalize_kernel<<<  1, 256, 0, stream>>>(partials, out);
}